// Round 5
// baseline (309.091 us; speedup 1.0000x reference)
//
#include <hip/hip_runtime.h>
#include <cstdint>
#include <cstddef>

// ---------------------------------------------------------------------------
// SpatialGRU 32x32, B=64, U=64, C=64. Persistent: 32 rows x 4 batch-tiles
// (bid = row*4+bt). Cross-row h via global states + per-wave flags (agent
// scope). R5: GEMM1 split around the h_top handoff — K=64:256 (hL,hD,s) and
// GEMM2's s-chunk computed BEFORE the poll (acc held in regs); only K=0:64
// + epilogue + GEMM2 r-chunks remain after. Flag==1 vs 0xAA poison -> no
// zero-flags kernel (single launch). 4 syncthreads/cell.
// ---------------------------------------------------------------------------

#define LDIM   32
#define BATCH  64
#define UNITS  64
#define CHAN   64
#define NBT    4
#define BT     16
#define TPB    512

typedef _Float16 f16;
typedef _Float16 f16x8 __attribute__((ext_vector_type(8)));
typedef float    f32x4 __attribute__((ext_vector_type(4)));

__global__ __launch_bounds__(TPB, 2) void spatial_gru_kernel(
    const float* __restrict__ x,     // (B, C, 32, 32)
    const float* __restrict__ W,     // (256, 448)
    const float* __restrict__ Urec,  // (192, 64)
    const float* __restrict__ bias,  // (512,)
    const float* __restrict__ Wij,   // (64, 64)
    float* __restrict__ out,         // (B, U)
    int* __restrict__ flags,
    float* __restrict__ states)      // (32, 32, B, U)
{
    const int bid = blockIdx.x;
    const int row = bid >> 2;
    const int bt  = bid & 3;
    const int b0  = bt * BT;
    const int t   = (int)threadIdx.x;
    const int u   = t & 63;
    const int g   = t >> 6;          // wave id 0..7 (uniform); also batch base
    const int l15 = t & 15;          // MFMA n-col / A-row lane
    const int lq  = (t & 63) >> 4;   // MFMA k-quad

    // ---- LDS ----
    // qf  : GEMM1 A (f16)  [b][k]  k: 0:64 hT | 64:128 hL | 128:192 hD | 192:256 s
    // rf  : GEMM2 A (f16)  [b][k]  k: 0:192 r*{hL,hT,hD} | 192:256 s
    // qs32: fp32 state     [b][c]  c: 0:64 hT | 64:128 hL | 128:192 hD
    // Gsz : z logits fp32  [b][n]  n: 0:256
    // pacc: GEMM2 partials [w][b][n] (wave-private slices, plain stores)
    __shared__ __attribute__((aligned(16))) f16 qf[BT][264];
    __shared__ __attribute__((aligned(16))) f16 rf[BT][264];
    __shared__ float qs32[BT][204];
    __shared__ float Gsz [BT][260];
    __shared__ float pacc[4][BT][68];

    // ---- GEMM1 weights resident in registers (waves 0..6: 64 cols each) ----
    f16x8 wreg[4][8];
    float bias1[4] = {0.f, 0.f, 0.f, 0.f};
    if (g < 7) {
        const int nb = g * 64 + l15;
#pragma unroll
        for (int T = 0; T < 4; ++T) {
            bias1[T] = bias[nb + 16 * T];
#pragma unroll
            for (int s = 0; s < 8; ++s) {
                f16x8 v;
#pragma unroll
                for (int jj = 0; jj < 8; ++jj) {
                    int kk = s * 32 + lq * 8 + jj;
                    v[jj] = (f16)W[(size_t)kk * 448 + nb + 16 * T];
                }
                wreg[T][s] = v;
            }
        }
    }
    // ---- GEMM2 weights: wave g holds k-chunk [(g&3)*64, +64) of [Urec;Wij]
    // (waves 4..7 use theirs: 0,64,128 = r-chunks; 192 = s-chunk on wave 7)
    f16x8 wreg2[4][2];
    {
        const int kb = (g & 3) * 64;
#pragma unroll
        for (int T = 0; T < 4; ++T) {
            const int nn = T * 16 + l15;
#pragma unroll
            for (int s = 0; s < 2; ++s) {
                f16x8 v;
#pragma unroll
                for (int jj = 0; jj < 8; ++jj) {
                    int kk = kb + s * 32 + lq * 8 + jj;
                    float wv = (kk < 192) ? Urec[kk * 64 + nn] : Wij[(kk - 192) * 64 + nn];
                    v[jj] = (f16)wv;
                }
                wreg2[T][s] = v;
            }
        }
    }
    const float bij = bias[448 + u];

    // ---- zero initial state (hT/hL/hD = 0) ----
    for (int idx = t; idx < 192 * BT; idx += TPB) {
        int b = idx & 15, k = idx >> 4;
        qs32[b][k] = 0.f;
        qf[b][k] = (f16)0.f;
    }

    // x: this thread handles channel u, batches b0+g and b0+g+8
    const size_t xb0 = (size_t)(b0 + g) * 65536 + (size_t)u * 1024 + (size_t)row * 32;
    const size_t xb1 = xb0 + (size_t)8 * 65536;
    {   // stage x(j=0)
        float x0 = x[xb0], x1 = x[xb1];
        qf[g][192 + u]     = (f16)x0;  rf[g][192 + u]     = (f16)x0;
        qf[g + 8][192 + u] = (f16)x1;  rf[g + 8][192 + u] = (f16)x1;
    }
    __syncthreads();

    for (int j = 0; j < LDIM; ++j) {
        // prefetch next cell's x (consumed in [F])
        float nx0 = 0.f, nx1 = 0.f;
        if (j < LDIM - 1) { nx0 = x[xb0 + j + 1]; nx1 = x[xb1 + j + 1]; }

        // ---- [W] wait-free work: GEMM1 over K=64:256 (hL,hD,s) on waves
        //      0..6; GEMM2 s-chunk (K=192:256) on wave 7 -> pacc[3] ----
        f32x4 acc[4];
        if (g < 7) {
#pragma unroll
            for (int T = 0; T < 4; ++T)
                acc[T] = (f32x4){bias1[T], bias1[T], bias1[T], bias1[T]};
#pragma unroll
            for (int s = 2; s < 8; ++s) {
                f16x8 a = *(const f16x8*)&qf[l15][s * 32 + lq * 8];
#pragma unroll
                for (int T = 0; T < 4; ++T)
                    acc[T] = __builtin_amdgcn_mfma_f32_16x16x32_f16(a, wreg[T][s], acc[T], 0, 0, 0);
            }
        } else {
            f32x4 a2[4];
#pragma unroll
            for (int T = 0; T < 4; ++T) a2[T] = (f32x4){0.f, 0.f, 0.f, 0.f};
#pragma unroll
            for (int s = 0; s < 2; ++s) {
                f16x8 a = *(const f16x8*)&rf[l15][192 + s * 32 + lq * 8];
#pragma unroll
                for (int T = 0; T < 4; ++T)
                    a2[T] = __builtin_amdgcn_mfma_f32_16x16x32_f16(a, wreg2[T][s], a2[T], 0, 0, 0);
            }
#pragma unroll
            for (int T = 0; T < 4; ++T)
#pragma unroll
                for (int r = 0; r < 4; ++r)
                    pacc[3][lq * 4 + r][T * 16 + l15] = a2[T][r];
        }

        // ---- [P] per-wave poll for (row-1, j); load + stage h_top ----
        float ht0 = 0.f, ht1 = 0.f;
        if (row > 0) {
            const int* fl = flags + (((row - 1) * LDIM + j) * NBT + bt) * 8 + g;
            while (__hip_atomic_load(fl, __ATOMIC_RELAXED, __HIP_MEMORY_SCOPE_AGENT) != 1) {
                __builtin_amdgcn_s_sleep(1);
            }
            asm volatile("" ::: "memory");
            const float* sp = states + (((size_t)(row - 1) * LDIM + j) * BATCH + b0) * UNITS;
            ht0 = __hip_atomic_load(sp + (size_t)g * 64 + u,
                                    __ATOMIC_RELAXED, __HIP_MEMORY_SCOPE_AGENT);
            ht1 = __hip_atomic_load(sp + (size_t)(g + 8) * 64 + u,
                                    __ATOMIC_RELAXED, __HIP_MEMORY_SCOPE_AGENT);
        }
        qs32[g][u]     = ht0;  qf[g][u]     = (f16)ht0;
        qs32[g + 8][u] = ht1;  qf[g + 8][u] = (f16)ht1;
        __syncthreads();   // s1 — hT staged by all waves

        // ---- [C2] GEMM1 remainder K=0:64 + epilogue ----
        if (g < 7) {
#pragma unroll
            for (int s = 0; s < 2; ++s) {
                f16x8 a = *(const f16x8*)&qf[l15][s * 32 + lq * 8];
#pragma unroll
                for (int T = 0; T < 4; ++T)
                    acc[T] = __builtin_amdgcn_mfma_f32_16x16x32_f16(a, wreg[T][s], acc[T], 0, 0, 0);
            }
            if (g < 3) {
                // g=0: r for hL (qs32 col 64+.), g=1: hT (col .), g=2: hD (col 128+.)
                const int colbase = (g == 0) ? 64 : (g == 1) ? 0 : 128;
#pragma unroll
                for (int T = 0; T < 4; ++T)
#pragma unroll
                    for (int r = 0; r < 4; ++r) {
                        float rr = 1.f / (1.f + __expf(-acc[T][r]));
                        int b = lq * 4 + r;
                        float hv = qs32[b][colbase + T * 16 + l15];
                        rf[b][g * 64 + T * 16 + l15] = (f16)(rr * hv);
                    }
            } else {
                const int zb = (g - 3) * 64;
#pragma unroll
                for (int T = 0; T < 4; ++T)
#pragma unroll
                    for (int r = 0; r < 4; ++r)
                        Gsz[lq * 4 + r][zb + T * 16 + l15] = acc[T][r];
            }
        }
        __syncthreads();   // s2 — rf (r-part) + Gsz ready

        // ---- [E] GEMM2 r-chunks: waves 4..6, K=(g-4)*64, private pacc ----
        if (g >= 4 && g < 7) {
            const int w  = g - 4;
            const int kb = w * 64;
            f32x4 a2[4];
#pragma unroll
            for (int T = 0; T < 4; ++T) a2[T] = (f32x4){0.f, 0.f, 0.f, 0.f};
#pragma unroll
            for (int s = 0; s < 2; ++s) {
                f16x8 a = *(const f16x8*)&rf[l15][kb + s * 32 + lq * 8];
#pragma unroll
                for (int T = 0; T < 4; ++T)
                    a2[T] = __builtin_amdgcn_mfma_f32_16x16x32_f16(a, wreg2[T][s], a2[T], 0, 0, 0);
            }
#pragma unroll
            for (int T = 0; T < 4; ++T)
#pragma unroll
                for (int r = 0; r < 4; ++r)
                    pacc[w][lq * 4 + r][T * 16 + l15] = a2[T][r];
        }
        __syncthreads();   // s3 — pacc ready

        // ---- [F] tanh + softmax + combine; store EARLY, rotate while
        //      stores drain, then per-wave drain + flag ----
        float hvv[2], hTv[2];
#pragma unroll
        for (int i = 0; i < 2; ++i) {
            int b = g + 8 * i;
            float hhv = bij + pacc[0][b][u] + pacc[1][b][u] + pacc[2][b][u] + pacc[3][b][u];
            float e2 = __expf(2.f * hhv);
            float th = 1.f - 2.f / (e2 + 1.f);          // tanh
            float zi = Gsz[b][u],       zl = Gsz[b][64 + u];
            float zt = Gsz[b][128 + u], zd = Gsz[b][192 + u];
            float mx = fmaxf(fmaxf(zi, zl), fmaxf(zt, zd));
            float ei = __expf(zi - mx), el = __expf(zl - mx);
            float et = __expf(zt - mx), ed = __expf(zd - mx);
            float inv = 1.f / (ei + el + et + ed);
            float hT = qs32[b][u], hL = qs32[b][64 + u], hD = qs32[b][128 + u];
            float hv = (el * hL + et * hT + ed * hD + ei * th) * inv;
            hvv[i] = hv; hTv[i] = hT;
            __hip_atomic_store(
                states + (((size_t)row * LDIM + j) * BATCH + b0 + b) * UNITS + u,
                hv, __ATOMIC_RELAXED, __HIP_MEMORY_SCOPE_AGENT);
        }
        if (row == LDIM - 1 && j == LDIM - 1) {
            out[(size_t)(b0 + g) * UNITS + u]     = hvv[0];
            out[(size_t)(b0 + g + 8) * UNITS + u] = hvv[1];
        }
        // rotations + next-x staging overlap the store drain
#pragma unroll
        for (int i = 0; i < 2; ++i) {
            int b = g + 8 * i;
            qs32[b][128 + u] = hTv[i];      // hD <- hT
            qs32[b][64 + u]  = hvv[i];      // hL <- h_new
            f16 htf = qf[b][u];
            qf[b][128 + u] = htf;
            qf[b][64 + u]  = (f16)hvv[i];
        }
        qf[g][192 + u]     = (f16)nx0;  rf[g][192 + u]     = (f16)nx0;
        qf[g + 8][192 + u] = (f16)nx1;  rf[g + 8][192 + u] = (f16)nx1;

        asm volatile("s_waitcnt vmcnt(0)" ::: "memory");
        if (u == 0) {
            __hip_atomic_store(flags + ((row * LDIM + j) * NBT + bt) * 8 + g, 1,
                               __ATOMIC_RELAXED, __HIP_MEMORY_SCOPE_AGENT);
        }
        __syncthreads();   // s4 — rotations/x-staging visible for next [W]
    }
}

extern "C" void kernel_launch(void* const* d_in, const int* in_sizes, int n_in,
                              void* d_out, int out_size, void* d_ws, size_t ws_size,
                              hipStream_t stream) {
    const float* x    = (const float*)d_in[0];
    const float* W    = (const float*)d_in[1];
    const float* Urec = (const float*)d_in[2];
    const float* bias = (const float*)d_in[3];
    const float* Wij  = (const float*)d_in[4];
    float* out = (float*)d_out;

    // flags: 32*32*4*8 ints = 128 KB (poison 0xAA... != 1 -> no zeroing needed)
    int*   flags  = (int*)d_ws;
    float* states = (float*)((char*)d_ws + 131072);

    spatial_gru_kernel<<<LDIM * NBT, TPB, 0, stream>>>(
        x, W, Urec, bias, Wij, out, flags, states);
}

// Round 6
// 263.741 us; speedup vs baseline: 1.1720x; 1.1720x over previous
//
#include <hip/hip_runtime.h>
#include <cstdint>
#include <cstddef>

// ---------------------------------------------------------------------------
// SpatialGRU 32x32, B=64, U=64, C=64. Persistent: 32 rows x 4 batch-tiles
// (bid = row*4+bt). R6: flag-free handoff — h_top crosses WGs as ONE dword
// per lane (2 x f16, LSB forced to 1 = validity marker; ws poison 0xAA can
// never satisfy both LSBs). Consumer polls its own dword (single load, no
// dependent flag->data chain); producer does a plain agent store (no vmcnt
// drain, no flag). R4's 3-barrier loop; wave 7 runs GEMM2's s-chunk in [C].
// ---------------------------------------------------------------------------

#define LDIM   32
#define BATCH  64
#define UNITS  64
#define CHAN   64
#define NBT    4
#define BT     16
#define TPB    512

typedef _Float16 f16;
typedef _Float16 f16x8 __attribute__((ext_vector_type(8)));
typedef float    f32x4 __attribute__((ext_vector_type(4)));

__global__ __launch_bounds__(TPB, 2) void spatial_gru_kernel(
    const float* __restrict__ x,     // (B, C, 32, 32)
    const float* __restrict__ W,     // (256, 448)
    const float* __restrict__ Urec,  // (192, 64)
    const float* __restrict__ bias,  // (512,)
    const float* __restrict__ Wij,   // (64, 64)
    float* __restrict__ out,         // (B, U)
    uint32_t* __restrict__ hbuf)     // (32, 32, NBT, 512) packed 2xf16|LSB
{
    const int bid = blockIdx.x;
    const int row = bid >> 2;
    const int bt  = bid & 3;
    const int b0  = bt * BT;
    const int t   = (int)threadIdx.x;
    const int u   = t & 63;
    const int g   = t >> 6;          // wave id 0..7; also batch base
    const int l15 = t & 15;          // MFMA n-col / A-row lane
    const int lq  = (t & 63) >> 4;   // MFMA k-quad

    // ---- LDS ----
    // qf  : GEMM1 A (f16)  [b][k]  k: 0:64 hT | 64:128 hL | 128:192 hD | 192:256 s
    // rf  : GEMM2 A (f16)  [b][k]  k: 0:192 r*{hL,hT,hD}  (s read from qf)
    // qs32: fp32 state     [b][c]  c: 0:64 hT | 64:128 hL | 128:192 hD
    // Gsz : z logits fp32  [b][n]  n: 0:256
    // pacc: GEMM2 partials [w][b][n] (wave-private slices, plain stores)
    __shared__ __attribute__((aligned(16))) f16 qf[BT][264];
    __shared__ __attribute__((aligned(16))) f16 rf[BT][200];
    __shared__ float qs32[BT][204];
    __shared__ float Gsz [BT][260];
    __shared__ float pacc[4][BT][68];

    // ---- GEMM1 weights resident in registers (waves 0..6: 64 cols each) ----
    f16x8 wreg[4][8];
    float bias1[4] = {0.f, 0.f, 0.f, 0.f};
    if (g < 7) {
        const int nb = g * 64 + l15;
#pragma unroll
        for (int T = 0; T < 4; ++T) {
            bias1[T] = bias[nb + 16 * T];
#pragma unroll
            for (int s = 0; s < 8; ++s) {
                f16x8 v;
#pragma unroll
                for (int jj = 0; jj < 8; ++jj) {
                    int kk = s * 32 + lq * 8 + jj;
                    v[jj] = (f16)W[(size_t)kk * 448 + nb + 16 * T];
                }
                wreg[T][s] = v;
            }
        }
    }
    // ---- GEMM2 weights: wave g holds k-chunk [(g&3)*64, +64) of [Urec;Wij]
    //      (waves 4,5,6 -> r-chunks k=0,64,128; wave 7 -> s-chunk k=192) ----
    f16x8 wreg2[4][2];
    {
        const int kb = (g & 3) * 64;
#pragma unroll
        for (int T = 0; T < 4; ++T) {
            const int nn = T * 16 + l15;
#pragma unroll
            for (int s = 0; s < 2; ++s) {
                f16x8 v;
#pragma unroll
                for (int jj = 0; jj < 8; ++jj) {
                    int kk = kb + s * 32 + lq * 8 + jj;
                    float wv = (kk < 192) ? Urec[kk * 64 + nn] : Wij[(kk - 192) * 64 + nn];
                    v[jj] = (f16)wv;
                }
                wreg2[T][s] = v;
            }
        }
    }
    const float bij = bias[448 + u];

    // ---- zero initial state (hT/hL/hD = 0) ----
    for (int idx = t; idx < 192 * BT; idx += TPB) {
        int b = idx & 15, k = idx >> 4;
        qs32[b][k] = 0.f;
        qf[b][k] = (f16)0.f;
    }

    // x: this thread handles channel u, batches b0+g and b0+g+8
    const size_t xb0 = (size_t)(b0 + g) * 65536 + (size_t)u * 1024 + (size_t)row * 32;
    const size_t xb1 = xb0 + (size_t)8 * 65536;
    {   // stage x(j=0)
        float x0 = x[xb0], x1 = x[xb1];
        qf[g][192 + u]     = (f16)x0;
        qf[g + 8][192 + u] = (f16)x1;
    }
    __syncthreads();

    for (int j = 0; j < LDIM; ++j) {
        // ---- [A] self-validating poll for (row-1,j); unpack + stage hT ----
        float ht0 = 0.f, ht1 = 0.f;
        f16 hf0 = (f16)0.f, hf1 = (f16)0.f;
        if (row > 0) {
            const uint32_t* sp =
                hbuf + ((((size_t)(row - 1) * LDIM + j) * NBT + bt) << 9) + (g << 6) + u;
            uint32_t w = __hip_atomic_load(sp, __ATOMIC_RELAXED, __HIP_MEMORY_SCOPE_AGENT);
            while ((w & 0x00010001u) != 0x00010001u) {
                __builtin_amdgcn_s_sleep(1);
                w = __hip_atomic_load(sp, __ATOMIC_RELAXED, __HIP_MEMORY_SCOPE_AGENT);
            }
            uint16_t lo = (uint16_t)(w & 0xFFFFu), hi = (uint16_t)(w >> 16);
            hf0 = __builtin_bit_cast(f16, lo);
            hf1 = __builtin_bit_cast(f16, hi);
            ht0 = (float)hf0;
            ht1 = (float)hf1;
        }
        qs32[g][u]     = ht0;  qf[g][u]     = hf0;
        qs32[g + 8][u] = ht1;  qf[g + 8][u] = hf1;
        __syncthreads();   // s1 — hT staged

        // prefetch next cell's x (consumed at end of [F])
        float nx0 = 0.f, nx1 = 0.f;
        if (j < LDIM - 1) { nx0 = x[xb0 + j + 1]; nx1 = x[xb1 + j + 1]; }

        // ---- [C] GEMM1 (waves 0..6) + fused sigmoid on waves 0..2;
        //      wave 7: GEMM2 s-chunk (k=192:256, reads x from qf) ----
        if (g < 7) {
            f32x4 acc[4];
#pragma unroll
            for (int T = 0; T < 4; ++T)
                acc[T] = (f32x4){bias1[T], bias1[T], bias1[T], bias1[T]};
#pragma unroll
            for (int s = 0; s < 8; ++s) {
                f16x8 a = *(const f16x8*)&qf[l15][s * 32 + lq * 8];
#pragma unroll
                for (int T = 0; T < 4; ++T)
                    acc[T] = __builtin_amdgcn_mfma_f32_16x16x32_f16(a, wreg[T][s], acc[T], 0, 0, 0);
            }
            if (g < 3) {
                // g=0: r*hL (qs32 col 64+.), g=1: r*hT (col .), g=2: r*hD (col 128+.)
                const int colbase = (g == 0) ? 64 : (g == 1) ? 0 : 128;
#pragma unroll
                for (int T = 0; T < 4; ++T)
#pragma unroll
                    for (int r = 0; r < 4; ++r) {
                        float rr = 1.f / (1.f + __expf(-acc[T][r]));
                        int b = lq * 4 + r;
                        float hv = qs32[b][colbase + T * 16 + l15];
                        rf[b][g * 64 + T * 16 + l15] = (f16)(rr * hv);
                    }
            } else {
                const int zb = (g - 3) * 64;
#pragma unroll
                for (int T = 0; T < 4; ++T)
#pragma unroll
                    for (int r = 0; r < 4; ++r)
                        Gsz[lq * 4 + r][zb + T * 16 + l15] = acc[T][r];
            }
        } else {
            f32x4 a2[4];
#pragma unroll
            for (int T = 0; T < 4; ++T) a2[T] = (f32x4){0.f, 0.f, 0.f, 0.f};
#pragma unroll
            for (int s = 0; s < 2; ++s) {
                f16x8 a = *(const f16x8*)&qf[l15][192 + s * 32 + lq * 8];
#pragma unroll
                for (int T = 0; T < 4; ++T)
                    a2[T] = __builtin_amdgcn_mfma_f32_16x16x32_f16(a, wreg2[T][s], a2[T], 0, 0, 0);
            }
#pragma unroll
            for (int T = 0; T < 4; ++T)
#pragma unroll
                for (int r = 0; r < 4; ++r)
                    pacc[3][lq * 4 + r][T * 16 + l15] = a2[T][r];
        }
        __syncthreads();   // s2 — rf + Gsz + pacc[3] ready

        // ---- [E] GEMM2 r-chunks: waves 4..6, k=(g-4)*64, private pacc ----
        if (g >= 4 && g < 7) {
            const int w  = g - 4;
            const int kb = w * 64;
            f32x4 a2[4];
#pragma unroll
            for (int T = 0; T < 4; ++T) a2[T] = (f32x4){0.f, 0.f, 0.f, 0.f};
#pragma unroll
            for (int s = 0; s < 2; ++s) {
                f16x8 a = *(const f16x8*)&rf[l15][kb + s * 32 + lq * 8];
#pragma unroll
                for (int T = 0; T < 4; ++T)
                    a2[T] = __builtin_amdgcn_mfma_f32_16x16x32_f16(a, wreg2[T][s], a2[T], 0, 0, 0);
            }
#pragma unroll
            for (int T = 0; T < 4; ++T)
#pragma unroll
                for (int r = 0; r < 4; ++r)
                    pacc[w][lq * 4 + r][T * 16 + l15] = a2[T][r];
        }
        __syncthreads();   // s3 — pacc ready

        // ---- [F] tanh + softmax + combine; packed self-validating store;
        //      rotate + stage next x (no drain, no flag, no barrier) ----
        float hvv[2], hTv[2];
#pragma unroll
        for (int i = 0; i < 2; ++i) {
            int b = g + 8 * i;
            float hhv = bij + pacc[0][b][u] + pacc[1][b][u] + pacc[2][b][u] + pacc[3][b][u];
            float e2 = __expf(2.f * hhv);
            float th = 1.f - 2.f / (e2 + 1.f);          // tanh
            float zi = Gsz[b][u],       zl = Gsz[b][64 + u];
            float zt = Gsz[b][128 + u], zd = Gsz[b][192 + u];
            float mx = fmaxf(fmaxf(zi, zl), fmaxf(zt, zd));
            float ei = __expf(zi - mx), el = __expf(zl - mx);
            float et = __expf(zt - mx), ed = __expf(zd - mx);
            float inv = 1.f / (ei + el + et + ed);
            float hT = qs32[b][u], hL = qs32[b][64 + u], hD = qs32[b][128 + u];
            float hv = (el * hL + et * hT + ed * hD + ei * th) * inv;
            hvv[i] = hv; hTv[i] = hT;
        }
        // handoff: pack 2xf16 with LSB=1 validity, single agent store
        {
            uint16_t lo = (uint16_t)(__builtin_bit_cast(uint16_t, (f16)hvv[0]) | 1u);
            uint16_t hi = (uint16_t)(__builtin_bit_cast(uint16_t, (f16)hvv[1]) | 1u);
            uint32_t pw = ((uint32_t)hi << 16) | lo;
            __hip_atomic_store(
                hbuf + ((((size_t)row * LDIM + j) * NBT + bt) << 9) + (g << 6) + u,
                pw, __ATOMIC_RELAXED, __HIP_MEMORY_SCOPE_AGENT);
        }
        if (row == LDIM - 1 && j == LDIM - 1) {
            out[(size_t)(b0 + g) * UNITS + u]     = hvv[0];
            out[(size_t)(b0 + g + 8) * UNITS + u] = hvv[1];
        }
        // rotations (thread-own slots): hD <- hT, hL <- h_new; stage next x
#pragma unroll
        for (int i = 0; i < 2; ++i) {
            int b = g + 8 * i;
            qs32[b][128 + u] = hTv[i];
            qs32[b][64 + u]  = hvv[i];
            f16 htf = qf[b][u];
            qf[b][128 + u] = htf;
            qf[b][64 + u]  = (f16)hvv[i];
        }
        qf[g][192 + u]     = (f16)nx0;
        qf[g + 8][192 + u] = (f16)nx1;
        // next [A] writes only thread-own slots; s1 covers cross-wave visibility
    }
}

extern "C" void kernel_launch(void* const* d_in, const int* in_sizes, int n_in,
                              void* d_out, int out_size, void* d_ws, size_t ws_size,
                              hipStream_t stream) {
    const float* x    = (const float*)d_in[0];
    const float* W    = (const float*)d_in[1];
    const float* Urec = (const float*)d_in[2];
    const float* bias = (const float*)d_in[3];
    const float* Wij  = (const float*)d_in[4];
    float* out = (float*)d_out;

    // hbuf: 32*32*4*512 dwords = 8 MB. Harness re-poisons ws with 0xAA each
    // launch; 0xAAAAAAAA fails the (w & 0x10001)==0x10001 validity test.
    uint32_t* hbuf = (uint32_t*)d_ws;

    spatial_gru_kernel<<<LDIM * NBT, TPB, 0, stream>>>(
        x, W, Urec, bias, Wij, out, hbuf);
}